// Round 9
// baseline (27378.485 us; speedup 1.0000x reference)
//
#include <hip/hip_runtime.h>
#include <hip/hip_bf16.h>
#include <stdint.h>

#define BQ 16
#define TT 4096
#define II 128
#define HH 256
#define RN 8       // ring slots (power of 2); phase flips every RN steps

typedef __attribute__((ext_vector_type(8))) short bf16x8;  // 8 bf16 (4 regs)
typedef __attribute__((ext_vector_type(4))) float f32x4;
typedef unsigned short ushort_t;
typedef unsigned int uint_t;
typedef unsigned long long u64t;

__device__ __forceinline__ ushort_t bf16r(float x) {
    __hip_bfloat16 h = __float2bfloat16(x);   // RTN
    union { __hip_bfloat16 h; ushort_t u; } c; c.h = h; return c.u;
}
__device__ __forceinline__ float f32up(ushort_t u) {
    union { uint_t i; float f; } c; c.i = ((uint_t)u) << 16; return c.f;
}
__device__ __forceinline__ float sigf(float x) {
    return __builtin_amdgcn_rcpf(1.f + __expf(-x));
}
__device__ __forceinline__ float tanhfast(float x) {
    float xc = fminf(fmaxf(x, -15.f), 15.f);
    float e = __expf(2.f * xc);
    return (e - 1.f) * __builtin_amdgcn_rcpf(e + 1.f);
}
// relaxed agent-scope coherent ops (MALL-coherent, no L2 inv/wb fences)
__device__ __forceinline__ u64t ldq(const u64t* p) {
    return __hip_atomic_load(p, __ATOMIC_RELAXED, __HIP_MEMORY_SCOPE_AGENT);
}
__device__ __forceinline__ void stq(u64t* p, u64t v) {
    __hip_atomic_store(p, v, __ATOMIC_RELAXED, __HIP_MEMORY_SCOPE_AGENT);
}
// validity: biased h lies in (base-1, base+1); other phase / zeros are far away
__device__ __forceinline__ int ok2(u64t d, float base) {
    float a = __uint_as_float((uint_t)d);
    float b = __uint_as_float((uint_t)(d >> 32));
    return (fabsf(a - base) < 1.5f) && (fabsf(b - base) < 1.5f);
}

#define MFA(ACC, A, B)                                                          \
    asm volatile("v_mfma_f32_16x16x32_bf16 %0, %1, %2, %0"                      \
                 : "+v"(ACC) : "v"(A), "a"(B))
__device__ __forceinline__ f32x4 MFI(bf16x8 a, bf16x8 b, f32x4 c) {
    return __builtin_amdgcn_mfma_f32_16x16x32_bf16(a, b, c, 0, 0, 0);
}

struct WPair { bf16x8 h, l; };
__device__ __forceinline__ WPair wsplit(const float* p) {
    float4 a = *(const float4*)p;
    float4 b = *(const float4*)(p + 4);
    float vv[8] = {a.x, a.y, a.z, a.w, b.x, b.y, b.z, b.w};
    WPair r;
#pragma unroll
    for (int j = 0; j < 8; j++) {
        ushort_t hh = bf16r(vv[j]);
        r.h[j] = (short)hh;
        r.l[j] = (short)bf16r(vv[j] - f32up(hh));
    }
    return r;
}
#define LOADW(H, L, P)                                                          \
    { WPair _t = wsplit(P); H = _t.h; L = _t.l;                                 \
      asm volatile("" : "+a"(H), "+a"(L)); }
#define LOADWH(H, P)                                                            \
    { WPair _t = wsplit(P); H = _t.h; asm volatile("" : "+a"(H)); }

// 4 u64 (8 biased f32) -> hi/lo bf16x8 A-fragments
__device__ __forceinline__ void cvt8(const u64t* d, float base, bf16x8* H, bf16x8* L) {
    bf16x8 h, l;
#pragma unroll
    for (int i = 0; i < 4; i++) {
        float a = __uint_as_float((uint_t)d[i]) - base;
        float b = __uint_as_float((uint_t)(d[i] >> 32)) - base;
        ushort_t ha = bf16r(a), hb = bf16r(b);
        h[2*i]   = (short)ha;  h[2*i+1] = (short)hb;
        l[2*i]   = (short)bf16r(a - f32up(ha));
        l[2*i+1] = (short)bf16r(b - f32up(hb));
    }
    *H = h; *L = l;
}

// xw[t-t0][b][n] = b0[n] + x[b][t][:] . Wih0[n][:]   (split-bf16 ~ fp32)
__global__ __launch_bounds__(256, 1)
void xw_gemm(const float* __restrict__ x, const float* __restrict__ Wih0,
             const float* __restrict__ b0v, float* __restrict__ xw, int t0)
{
    const int tid = threadIdx.x, lane = tid & 63, wv = tid >> 6;
    const int ln15 = lane & 15, kgrp = lane >> 4;
    const int tb = blockIdx.x >> 2, quarter = blockIdx.x & 3;
    const int n0 = quarter * 256 + wv * 64;

    bf16x8 w_h[4][4], w_l[4][4];
    float bb[4];
#pragma unroll
    for (int c = 0; c < 4; c++) {
        const int nr = n0 + c * 16 + ln15;
        const float* p = Wih0 + (size_t)nr * II + kgrp * 8;
#pragma unroll
        for (int k = 0; k < 4; k++) {
            WPair t = wsplit(p + k * 32);
            w_h[c][k] = t.h; w_l[c][k] = t.l;
        }
        bb[c] = b0v[nr];
    }
    for (int tt = 0; tt < 8; tt++) {
        const int t = t0 + tb * 8 + tt;
        bf16x8 ah[4], al[4];
#pragma unroll
        for (int k = 0; k < 4; k++) {
            WPair a = wsplit(x + ((size_t)ln15 * TT + t) * II + k * 32 + kgrp * 8);
            ah[k] = a.h; al[k] = a.l;
        }
        f32x4 acc[4];
#pragma unroll
        for (int c = 0; c < 4; c++) acc[c] = (f32x4){bb[c], bb[c], bb[c], bb[c]};
#pragma unroll
        for (int k = 0; k < 4; k++)
#pragma unroll
            for (int c = 0; c < 4; c++) {
                acc[c] = MFI(ah[k], w_h[c][k], acc[c]);
                acc[c] = MFI(al[k], w_h[c][k], acc[c]);
                acc[c] = MFI(ah[k], w_l[c][k], acc[c]);
            }
#pragma unroll
        for (int c = 0; c < 4; c++)
#pragma unroll
            for (int r = 0; r < 4; r++)
                xw[((size_t)(t - t0) * 16 + kgrp * 4 + r) * 1024 + n0 + c * 16 + ln15] = acc[c][r];
    }
}

// Fused 2-layer scan: 16 WGs x 256 thr (4 waves). WG w owns cols [w*16, w*16+16).
// wave 0,1 = L0 (kh = K-half of 256); wave 2,3 = L1 (kh half of h1 AND h2).
// Wave 0 also hosts the L0 pointwise update; wave 2 hosts L1 (one step behind:
// round s computes h1[s] and h2[s-1]).
// Rings hold h as BIASED f32 (phase base 4/8 alternating every RN steps):
// each 4B word self-validates -> consumers poll the data itself. No seq words,
// no producer drains. Gate partials join via padded LDS (2 barriers/round).
__global__ __launch_bounds__(256, 1)
void lstm_scan(const float* __restrict__ Whh0, const float* __restrict__ Wih1,
               const float* __restrict__ Whh1, const float* __restrict__ b1v,
               const float* __restrict__ xw,
               u64t* __restrict__ rg1, u64t* __restrict__ rg2,
               float* __restrict__ out, float* c0s, float* c1s,
               int t0, int tEnd)
{
    const int tid = threadIdx.x;
    const int lane = tid & 63;
    const int v = tid >> 6;            // wave 0..3
    const int ln15 = lane & 15, kgrp = lane >> 4;
    const int w = blockIdx.x;          // 0..15
    const int kh = v & 1;
    const int ub = lane >> 2, uj4 = (lane & 3) * 4;  // update-role mapping

    __shared__ float gP[2][2][4][16][17];  // [layer][kh][gate][batch][col]

    if (v < 2) {
        // =========================== layer 0 ===========================
        bf16x8 W0h0,W0h1,W0h2,W0h3, W0l0,W0l1,W0l2,W0l3;
        bf16x8 W1h0,W1h1,W1h2,W1h3, W1l0,W1l1,W1l2,W1l3;
        bf16x8 W2h0,W2h1,W2h2,W2h3, W2l0,W2l1,W2l2,W2l3;
        bf16x8 W3h0,W3h1,W3h2,W3h3, W3l0,W3l1,W3l2,W3l3;
#define LW0(Q)                                                                  \
        { const float* p_ = Whh0 + (size_t)(Q*256 + w*16 + ln15)*HH + kh*128 + kgrp*8; \
          LOADW(W##Q##h0, W##Q##l0, p_);      LOADW(W##Q##h1, W##Q##l1, p_+32); \
          LOADW(W##Q##h2, W##Q##l2, p_+64);   LOADW(W##Q##h3, W##Q##l3, p_+96); }
        LW0(0) LW0(1) LW0(2) LW0(3)
#undef LW0
        const int isUpd = (v == 0);
        float c4[4] = {0.f, 0.f, 0.f, 0.f};
        if (isUpd) {
            f32x4 cv = *(const f32x4*)(c0s + (size_t)ub * HH + w * 16 + uj4);
            c4[0]=cv[0]; c4[1]=cv[1]; c4[2]=cv[2]; c4[3]=cv[3];
        }

        for (int s = t0; s < tEnd; s++) {
            const int actL0 = (s < TT);
            f32x4 xv0, xv1, xv2, xv3;
            if (isUpd && actL0) {
                const float* xp = xw + ((size_t)(s - t0) * 16 + ub) * 1024 + w * 16 + uj4;
                xv0 = *(const f32x4*)(xp + 0);
                xv1 = *(const f32x4*)(xp + 256);
                xv2 = *(const f32x4*)(xp + 512);
                xv3 = *(const f32x4*)(xp + 768);
            }
            if (actL0 && s > 0) {
                const int ps = (s - 1) & (RN - 1);
                const float pb = (((s - 1) >> 3) & 1) ? 8.f : 4.f;
                const u64t* p = rg1 + ((size_t)ps * 16 + ln15) * 128 + kh * 64 + kgrp * 4;
                u64t d[16];
                while (1) {
                    int o = 1;
#pragma unroll
                    for (int f = 0; f < 4; f++)
#pragma unroll
                        for (int i = 0; i < 4; i++) {
                            u64t xq = ldq(p + f * 16 + i);
                            d[f * 4 + i] = xq; o &= ok2(xq, pb);
                        }
                    if (__all(o)) break;
                    __builtin_amdgcn_s_sleep(1);
                }
                bf16x8 Ah0,Al0,Ah1,Al1,Ah2,Al2,Ah3,Al3;
                cvt8(d + 0,  pb, &Ah0, &Al0);
                cvt8(d + 4,  pb, &Ah1, &Al1);
                cvt8(d + 8,  pb, &Ah2, &Al2);
                cvt8(d + 12, pb, &Ah3, &Al3);
                f32x4 a0 = {0,0,0,0}, a1 = a0, a2 = a0, a3 = a0;
#define T0(f)                                                                   \
                MFA(a0, Ah##f, W0h##f); MFA(a1, Ah##f, W1h##f);                 \
                MFA(a2, Ah##f, W2h##f); MFA(a3, Ah##f, W3h##f);                 \
                MFA(a0, Al##f, W0h##f); MFA(a1, Al##f, W1h##f);                 \
                MFA(a2, Al##f, W2h##f); MFA(a3, Al##f, W3h##f);                 \
                MFA(a0, Ah##f, W0l##f); MFA(a1, Ah##f, W1l##f);                 \
                MFA(a2, Ah##f, W2l##f); MFA(a3, Ah##f, W3l##f);
                T0(0) T0(1) T0(2) T0(3)
#undef T0
#pragma unroll
                for (int r = 0; r < 4; r++) {
                    gP[0][kh][0][kgrp * 4 + r][ln15] = a0[r];
                    gP[0][kh][1][kgrp * 4 + r][ln15] = a1[r];
                    gP[0][kh][2][kgrp * 4 + r][ln15] = a2[r];
                    gP[0][kh][3][kgrp * 4 + r][ln15] = a3[r];
                }
            }
            __syncthreads();   // bar1: gP ready
            float vv0=0.f, vv1=0.f, vv2=0.f, vv3=0.f;
            if (isUpd && actL0) {
                const float bs = ((s >> 3) & 1) ? 8.f : 4.f;
                float pr[4][4];
#pragma unroll
                for (int g = 0; g < 4; g++) {
                    const f32x4 xvg = (g == 0) ? xv0 : (g == 1) ? xv1 : (g == 2) ? xv2 : xv3;
#pragma unroll
                    for (int e = 0; e < 4; e++) {
                        float t = xvg[e];
                        if (s > 0) t += gP[0][0][g][ub][uj4 + e] + gP[0][1][g][ub][uj4 + e];
                        pr[g][e] = t;
                    }
                }
                float vo[4];
#pragma unroll
                for (int e = 0; e < 4; e++) {
                    const float iv = sigf(pr[0][e]), fv = sigf(pr[1][e]);
                    const float gv = tanhfast(pr[2][e]), ov = sigf(pr[3][e]);
                    c4[e] = fmaf(fv, c4[e], iv * gv);
                    vo[e] = ov * tanhfast(c4[e]) + bs;
                }
                vv0 = vo[0]; vv1 = vo[1]; vv2 = vo[2]; vv3 = vo[3];
            }
            __syncthreads();   // bar2: gP reads done (safe to rewrite next round)
            if (isUpd && actL0) {
                union { float f[2]; u64t u; } q0, q1;
                q0.f[0] = vv0; q0.f[1] = vv1; q1.f[0] = vv2; q1.f[1] = vv3;
                u64t* sp = rg1 + ((size_t)(s & (RN - 1)) * 16 + ub) * 128 + w * 8 + (uj4 >> 1);
                stq(sp, q0.u); stq(sp + 1, q1.u);
            }
        }
        if (isUpd) {
            f32x4 cv = {c4[0], c4[1], c4[2], c4[3]};
            *(f32x4*)(c0s + (size_t)ub * HH + w * 16 + uj4) = cv;
        }
    } else {
        // =========================== layer 1 ===========================
        bf16x8 I00,I01,I02,I03, I10,I11,I12,I13, I20,I21,I22,I23, I30,I31,I32,I33;
        bf16x8 H00,H01,H02,H03, H10,H11,H12,H13, H20,H21,H22,H23, H30,H31,H32,H33;
#define LW1(Q)                                                                  \
        { const float* pi_ = Wih1 + (size_t)(Q*256 + w*16 + ln15)*HH + kh*128 + kgrp*8; \
          LOADWH(I##Q##0, pi_);    LOADWH(I##Q##1, pi_+32);                     \
          LOADWH(I##Q##2, pi_+64); LOADWH(I##Q##3, pi_+96);                     \
          const float* ph_ = Whh1 + (size_t)(Q*256 + w*16 + ln15)*HH + kh*128 + kgrp*8; \
          LOADWH(H##Q##0, ph_);    LOADWH(H##Q##1, ph_+32);                     \
          LOADWH(H##Q##2, ph_+64); LOADWH(H##Q##3, ph_+96); }
        LW1(0) LW1(1) LW1(2) LW1(3)
#undef LW1
        float bb0 = 0.f, bb1 = 0.f, bb2 = 0.f, bb3 = 0.f;
        if (kh == 0) {
            bb0 = b1v[0*256 + w*16 + ln15];
            bb1 = b1v[1*256 + w*16 + ln15];
            bb2 = b1v[2*256 + w*16 + ln15];
            bb3 = b1v[3*256 + w*16 + ln15];
        }
        const int isUpd = (v == 2);
        float c4[4] = {0.f, 0.f, 0.f, 0.f};
        if (isUpd) {
            f32x4 cv = *(const f32x4*)(c1s + (size_t)ub * HH + w * 16 + uj4);
            c4[0]=cv[0]; c4[1]=cv[1]; c4[2]=cv[2]; c4[3]=cv[3];
        }

        for (int s = t0; s < tEnd; s++) {
            const int actL1 = (s >= 1);
            if (actL1) {
                const int ps = (s - 1) & (RN - 1);
                const float pb = (((s - 1) >> 3) & 1) ? 8.f : 4.f;
                const int qs = (s - 2) & (RN - 1);
                const float qb = (((s - 2) >> 3) & 1) ? 8.f : 4.f;
                const int has2 = (s >= 2);
                const u64t* p1 = rg1 + ((size_t)ps * 16 + ln15) * 128 + kh * 64 + kgrp * 4;
                const u64t* p2 = rg2 + ((size_t)qs * 16 + ln15) * 128 + kh * 64 + kgrp * 4;
                u64t d[16], e2[16];
                while (1) {
                    int o = 1;
#pragma unroll
                    for (int f = 0; f < 4; f++)
#pragma unroll
                        for (int i = 0; i < 4; i++) {
                            u64t xq = ldq(p1 + f * 16 + i);
                            d[f * 4 + i] = xq; o &= ok2(xq, pb);
                        }
                    if (has2) {
#pragma unroll
                        for (int f = 0; f < 4; f++)
#pragma unroll
                            for (int i = 0; i < 4; i++) {
                                u64t xq = ldq(p2 + f * 16 + i);
                                e2[f * 4 + i] = xq; o &= ok2(xq, qb);
                            }
                    }
                    if (__all(o)) break;
                    __builtin_amdgcn_s_sleep(1);
                }
                bf16x8 Ah0,Al0,Ah1,Al1,Ah2,Al2,Ah3,Al3;
                cvt8(d + 0,  pb, &Ah0, &Al0);
                cvt8(d + 4,  pb, &Ah1, &Al1);
                cvt8(d + 8,  pb, &Ah2, &Al2);
                cvt8(d + 12, pb, &Ah3, &Al3);
                f32x4 a0 = {bb0, bb0, bb0, bb0};
                f32x4 a1 = {bb1, bb1, bb1, bb1};
                f32x4 a2 = {bb2, bb2, bb2, bb2};
                f32x4 a3 = {bb3, bb3, bb3, bb3};
#define T1(f)                                                                   \
                MFA(a0, Ah##f, I0##f); MFA(a1, Ah##f, I1##f);                   \
                MFA(a2, Ah##f, I2##f); MFA(a3, Ah##f, I3##f);                   \
                MFA(a0, Al##f, I0##f); MFA(a1, Al##f, I1##f);                   \
                MFA(a2, Al##f, I2##f); MFA(a3, Al##f, I3##f);
                T1(0) T1(1) T1(2) T1(3)
#undef T1
                if (has2) {
                    bf16x8 Bh0,Bl0,Bh1,Bl1,Bh2,Bl2,Bh3,Bl3;
                    cvt8(e2 + 0,  qb, &Bh0, &Bl0);
                    cvt8(e2 + 4,  qb, &Bh1, &Bl1);
                    cvt8(e2 + 8,  qb, &Bh2, &Bl2);
                    cvt8(e2 + 12, qb, &Bh3, &Bl3);
#define T2(f)                                                                   \
                    MFA(a0, Bh##f, H0##f); MFA(a1, Bh##f, H1##f);               \
                    MFA(a2, Bh##f, H2##f); MFA(a3, Bh##f, H3##f);               \
                    MFA(a0, Bl##f, H0##f); MFA(a1, Bl##f, H1##f);               \
                    MFA(a2, Bl##f, H2##f); MFA(a3, Bl##f, H3##f);
                    T2(0) T2(1) T2(2) T2(3)
#undef T2
                }
#pragma unroll
                for (int r = 0; r < 4; r++) {
                    gP[1][kh][0][kgrp * 4 + r][ln15] = a0[r];
                    gP[1][kh][1][kgrp * 4 + r][ln15] = a1[r];
                    gP[1][kh][2][kgrp * 4 + r][ln15] = a2[r];
                    gP[1][kh][3][kgrp * 4 + r][ln15] = a3[r];
                }
            }
            __syncthreads();   // bar1
            float vv0=0.f, vv1=0.f, vv2=0.f, vv3=0.f;
            f32x4 ho = {0,0,0,0};
            if (isUpd && actL1) {
                const float bs = (((s - 1) >> 3) & 1) ? 8.f : 4.f;
                float pr[4][4];
#pragma unroll
                for (int g = 0; g < 4; g++)
#pragma unroll
                    for (int e = 0; e < 4; e++)
                        pr[g][e] = gP[1][0][g][ub][uj4 + e] + gP[1][1][g][ub][uj4 + e];
                float vo[4];
#pragma unroll
                for (int e = 0; e < 4; e++) {
                    const float iv = sigf(pr[0][e]), fv = sigf(pr[1][e]);
                    const float gv = tanhfast(pr[2][e]), ov = sigf(pr[3][e]);
                    c4[e] = fmaf(fv, c4[e], iv * gv);
                    const float hv = ov * tanhfast(c4[e]);
                    ho[e] = hv;
                    vo[e] = hv + bs;
                }
                vv0 = vo[0]; vv1 = vo[1]; vv2 = vo[2]; vv3 = vo[3];
            }
            __syncthreads();   // bar2
            if (isUpd && actL1) {
                *(f32x4*)(out + ((size_t)ub * TT + (s - 1)) * HH + w * 16 + uj4) = ho;
                union { float f[2]; u64t u; } q0, q1;
                q0.f[0] = vv0; q0.f[1] = vv1; q1.f[0] = vv2; q1.f[1] = vv3;
                u64t* sp = rg2 + ((size_t)((s - 1) & (RN - 1)) * 16 + ub) * 128 + w * 8 + (uj4 >> 1);
                stq(sp, q0.u); stq(sp + 1, q1.u);
            }
        }
        if (isUpd) {
            f32x4 cv = {c4[0], c4[1], c4[2], c4[3]};
            *(f32x4*)(c1s + (size_t)ub * HH + w * 16 + uj4) = cv;
        }
    }
}

extern "C" void kernel_launch(void* const* d_in, const int* in_sizes, int n_in,
                              void* d_out, int out_size, void* d_ws, size_t ws_size,
                              hipStream_t stream) {
    (void)in_sizes; (void)n_in; (void)out_size;
    const float* x    = (const float*)d_in[0];
    const float* Wih0 = (const float*)d_in[1];
    const float* Whh0 = (const float*)d_in[2];
    const float* b0   = (const float*)d_in[3];
    const float* Wih1 = (const float*)d_in[4];
    const float* Whh1 = (const float*)d_in[5];
    const float* b1   = (const float*)d_in[6];
    float* out = (float*)d_out;

    // ---- workspace carve ----
    char* ws = (char*)d_ws;
    u64t*  rg1 = (u64t*)ws;                      // [RN][16][128] u64 (128KB)
    u64t*  rg2 = rg1 + (size_t)RN * 16 * 128;    // 128KB
    float* c0s = (float*)(rg2 + (size_t)RN * 16 * 128);  // [16][256]
    float* c1s = c0s + BQ * HH;
    float* xw  = c1s + BQ * HH;                  // [TC][16][1024] f32
    const size_t fixedBytes = (size_t)((char*)xw - ws);

    int TC = TT;
    while (TC > 512 && fixedBytes + (size_t)TC * BQ * 1024 * 4 > ws_size) TC >>= 1;

    // zero rings + c-state (rings: 0.0 is invalid for every phase)
    hipMemsetAsync(ws, 0, fixedBytes, stream);

    for (int t0 = 0; t0 < TT; t0 += TC) {
        xw_gemm<<<(TC / 8) * 4, 256, 0, stream>>>(x, Wih0, b0, xw, t0);
        const int tEnd = t0 + TC + ((t0 + TC == TT) ? 1 : 0);
        lstm_scan<<<16, 256, 0, stream>>>(Whh0, Wih1, Whh1, b1, xw,
                                          rg1, rg2, out, c0s, c1s, t0, tEnd);
    }
}

// Round 11
// 17560.834 us; speedup vs baseline: 1.5591x; 1.5591x over previous
//
#include <hip/hip_runtime.h>
#include <hip/hip_bf16.h>
#include <stdint.h>

#define BQ 16
#define TT 4096
#define II 128
#define HH 256
#define RINGN 8
#define SEQPAD 32

typedef __attribute__((ext_vector_type(8))) short bf16x8;  // 8 bf16 (4 regs)
typedef __attribute__((ext_vector_type(4))) float f32x4;
typedef unsigned short ushort_t;
typedef unsigned long long u64t;

union U2 { struct { u64t a, b; } u; bf16x8 v; };

__device__ __forceinline__ ushort_t bf16r(float x) {
    __hip_bfloat16 h = __float2bfloat16(x);
    union { __hip_bfloat16 h; ushort_t u; } c; c.h = h; return c.u;
}
__device__ __forceinline__ float f32up(ushort_t u) {
    union { unsigned int i; float f; } c; c.i = ((unsigned int)u) << 16; return c.f;
}
__device__ __forceinline__ float sigf(float x) {
    return __builtin_amdgcn_rcpf(1.f + __expf(-x));
}
__device__ __forceinline__ float tanhfast(float x) {
    float xc = fminf(fmaxf(x, -15.f), 15.f);
    float e = __expf(2.f * xc);
    return (e - 1.f) * __builtin_amdgcn_rcpf(e + 1.f);
}
// relaxed agent-scope coherent ops (proven rounds 7/8: correct cross-XCD, no fences)
__device__ __forceinline__ u64t ldq(const u64t* p) {
    return __hip_atomic_load(p, __ATOMIC_RELAXED, __HIP_MEMORY_SCOPE_AGENT);
}
__device__ __forceinline__ void stq(u64t* p, u64t v) {
    __hip_atomic_store(p, v, __ATOMIC_RELAXED, __HIP_MEMORY_SCOPE_AGENT);
}

#define MFA(ACC, A, B)                                                          \
    asm volatile("v_mfma_f32_16x16x32_bf16 %0, %1, %2, %0"                      \
                 : "+v"(ACC) : "v"(A), "a"(B))
__device__ __forceinline__ f32x4 MFI(bf16x8 a, bf16x8 b, f32x4 c) {
    return __builtin_amdgcn_mfma_f32_16x16x32_bf16(a, b, c, 0, 0, 0);
}

struct WPair { bf16x8 h, l; };
__device__ __forceinline__ WPair wsplit(const float* p) {
    float4 a = *(const float4*)p;
    float4 b = *(const float4*)(p + 4);
    float vv[8] = {a.x, a.y, a.z, a.w, b.x, b.y, b.z, b.w};
    WPair r;
#pragma unroll
    for (int j = 0; j < 8; j++) {
        ushort_t hh = bf16r(vv[j]);
        r.h[j] = (short)hh;
        r.l[j] = (short)bf16r(vv[j] - f32up(hh));
    }
    return r;
}
#define LOADW(H, L, P)                                                          \
    { WPair _t = wsplit(P); H = _t.h; L = _t.l;                                 \
      asm volatile("" : "+a"(H), "+a"(L)); }
#define LOADWH(H, P)                                                            \
    { WPair _t = wsplit(P); H = _t.h; asm volatile("" : "+a"(H)); }

// seq layout: words 0..15 = seqA (h1, per WG x row-half), 16..31 = seqB (h2).
__device__ __forceinline__ void pollA(const int* seq, int need) {
    const int* p = seq + (threadIdx.x & 15) * SEQPAD;
    while (1) {
        int vv = __hip_atomic_load(p, __ATOMIC_RELAXED, __HIP_MEMORY_SCOPE_AGENT);
        if (__all(vv >= need)) break;
        __builtin_amdgcn_s_sleep(1);
    }
    asm volatile("" ::: "memory");
}
__device__ __forceinline__ void pollAB(const int* seq, int needA, int needB) {
    const int idx = threadIdx.x & 31;
    const int* p = seq + idx * SEQPAD;
    const int need = (idx < 16) ? needA : needB;
    while (1) {
        int vv = __hip_atomic_load(p, __ATOMIC_RELAXED, __HIP_MEMORY_SCOPE_AGENT);
        if (__all(vv >= need)) break;
        __builtin_amdgcn_s_sleep(1);
    }
    asm volatile("" ::: "memory");
}

// xw[t-t0][n][b] = b0[n] + x[b][t][:] . Wih0[n][:]   (split-bf16 ~ fp32)
__global__ __launch_bounds__(256, 1)
void xw_gemm(const float* __restrict__ x, const float* __restrict__ Wih0,
             const float* __restrict__ b0v, float* __restrict__ xw, int t0)
{
    const int tid = threadIdx.x, lane = tid & 63, wv = tid >> 6;
    const int ln15 = lane & 15, kgrp = lane >> 4;
    const int tb = blockIdx.x >> 2, quarter = blockIdx.x & 3;
    const int n0 = quarter * 256 + wv * 64;

    bf16x8 w_h[4][4], w_l[4][4];
    float bb[4];
#pragma unroll
    for (int c = 0; c < 4; c++) {
        const int nr = n0 + c * 16 + ln15;
        const float* p = Wih0 + (size_t)nr * II + kgrp * 8;
#pragma unroll
        for (int k = 0; k < 4; k++) {
            WPair t = wsplit(p + k * 32);
            w_h[c][k] = t.h; w_l[c][k] = t.l;
        }
        bb[c] = b0v[nr];
    }
    for (int tt = 0; tt < 8; tt++) {
        const int t = t0 + tb * 8 + tt;
        bf16x8 ah[4], al[4];
#pragma unroll
        for (int k = 0; k < 4; k++) {
            WPair a = wsplit(x + ((size_t)ln15 * TT + t) * II + k * 32 + kgrp * 8);
            ah[k] = a.h; al[k] = a.l;
        }
        f32x4 acc[4];
#pragma unroll
        for (int c = 0; c < 4; c++) acc[c] = (f32x4){bb[c], bb[c], bb[c], bb[c]};
#pragma unroll
        for (int k = 0; k < 4; k++)
#pragma unroll
            for (int c = 0; c < 4; c++) {
                acc[c] = MFI(ah[k], w_h[c][k], acc[c]);
                acc[c] = MFI(al[k], w_h[c][k], acc[c]);
                acc[c] = MFI(ah[k], w_l[c][k], acc[c]);
            }
#pragma unroll
        for (int c = 0; c < 4; c++)
            *(f32x4*)(xw + (((size_t)(t - t0) * 1024) + n0 + c * 16 + ln15) * 16 + kgrp * 4) = acc[c];
    }
}

// Fused 2-layer scan (round-8 protocol + single barrier/step).
// 8 WGs x 512 thr; WG w owns h1/h2 slice [w*32, w*32+32).
// Waves v<4: L0 compute (and phase-B update hosts); waves v>=4: L1 compute
// (one step behind: t1 = s-1). Gate partials in parity-double-buffered gP
// (pad 34 -> 2-way banks = free). Per-wave seq words: each updater wave
// stores its ring half, drains ITS OWN vmcnt, publishes its seq word; `out`
// HBM store issued after publication (ack off critical path).
__global__ __launch_bounds__(512, 2)
void lstm_ring(const float* __restrict__ Whh0, const float* __restrict__ Wih1,
               const float* __restrict__ Whh1, const float* __restrict__ b1v,
               const float* __restrict__ xw,
               u64t* r1h, u64t* r1l, u64t* r2h, u64t* r2l,
               float* out, float* c0s, float* c1s, int* seq,
               int t0, int tEnd)
{
    const int tid = threadIdx.x;
    const int lane = tid & 63;
    const int v = tid >> 6;
    const int ln15 = lane & 15, kgrp = lane >> 4;
    const int w = blockIdx.x;

    __shared__ float gP[2][2][2][4][16][34];  // [par][layer][kh][gate][batch][col]

    if (v < 4) {
        // ---------------- L0 compute + update host ----------------
        const int quad = v >> 1, kh = v & 1;
        const int qA = quad * 2, qB = quad * 2 + 1;
        const int r0 = qA * 256 + w * 32 + 0  + ln15;
        const int r1 = qA * 256 + w * 32 + 16 + ln15;
        const int r2 = qB * 256 + w * 32 + 0  + ln15;
        const int r3 = qB * 256 + w * 32 + 16 + ln15;

        bf16x8 B0h0,B0h1,B0h2,B0h3, B0l0,B0l1,B0l2,B0l3;
        bf16x8 B1h0,B1h1,B1h2,B1h3, B1l0,B1l1,B1l2,B1l3;
        bf16x8 B2h0,B2h1,B2h2,B2h3, B2l0,B2l1,B2l2,B2l3;
        bf16x8 B3h0,B3h1,B3h2,B3h3, B3l0,B3l1,B3l2,B3l3;
#define LW0(T, RT)                                                              \
        { const float* p = Whh0 + (size_t)(RT) * HH + kh * 128 + kgrp * 8;      \
          LOADW(B##T##h0, B##T##l0, p);      LOADW(B##T##h1, B##T##l1, p + 32); \
          LOADW(B##T##h2, B##T##l2, p + 64); LOADW(B##T##h3, B##T##l3, p + 96); }
        LW0(0, r0) LW0(1, r1) LW0(2, r2) LW0(3, r3)
#undef LW0

        float c4[4] = {0.f, 0.f, 0.f, 0.f};
        {
            const int ut = tid & 127;
            const int b = ut >> 3, j4v = (ut & 7) * 4;
            const float* cs = (tid < 128) ? c0s : c1s;
            if (tid < 256) {
                f32x4 cv = *(const f32x4*)(cs + (size_t)b * HH + w * 32 + j4v);
                c4[0]=cv[0]; c4[1]=cv[1]; c4[2]=cv[2]; c4[3]=cv[3];
            }
        }

        for (int s = t0; s < tEnd; s++) {
            const int par = s & 1;
            if (s < TT) {
                f32x4 a0, a1, a2, a3;
                if (kh == 0) {
                    const size_t xb = ((size_t)(s - t0) * 1024);
                    a0 = *(const f32x4*)(xw + (xb + r0) * 16 + kgrp * 4);
                    a1 = *(const f32x4*)(xw + (xb + r1) * 16 + kgrp * 4);
                    a2 = *(const f32x4*)(xw + (xb + r2) * 16 + kgrp * 4);
                    a3 = *(const f32x4*)(xw + (xb + r3) * 16 + kgrp * 4);
                } else {
                    a0 = (f32x4){0,0,0,0}; a1 = a0; a2 = a0; a3 = a0;
                }
                if (s > 0) {
                    pollA(seq, s);
                    const size_t rb = (size_t)((s - 1) & (RINGN - 1)) * 1024
                                    + (size_t)(kgrp * 16 + ln15) * 2;
                    U2 Ah0, Ah1, Ah2, Ah3, Al0, Al1, Al2, Al3;
#define RL0(k)                                                                  \
                    { const size_t o = rb + (size_t)(kh * 4 + k) * 128;         \
                      Ah##k.u.a = ldq(r1h + o); Ah##k.u.b = ldq(r1h + o + 1);   \
                      Al##k.u.a = ldq(r1l + o); Al##k.u.b = ldq(r1l + o + 1); }
                    RL0(0) RL0(1) RL0(2) RL0(3)
#undef RL0
#define MK0(k)                                                                  \
                    MFA(a0, Ah##k.v, B0h##k); MFA(a0, Al##k.v, B0h##k);         \
                    MFA(a0, Ah##k.v, B0l##k);                                   \
                    MFA(a1, Ah##k.v, B1h##k); MFA(a1, Al##k.v, B1h##k);         \
                    MFA(a1, Ah##k.v, B1l##k);                                   \
                    MFA(a2, Ah##k.v, B2h##k); MFA(a2, Al##k.v, B2h##k);         \
                    MFA(a2, Ah##k.v, B2l##k);                                   \
                    MFA(a3, Ah##k.v, B3h##k); MFA(a3, Al##k.v, B3h##k);         \
                    MFA(a3, Ah##k.v, B3l##k);
                    MK0(0) MK0(1) MK0(2) MK0(3)
#undef MK0
                }
#pragma unroll
                for (int r = 0; r < 4; r++) {
                    gP[par][0][kh][qA][kgrp * 4 + r][0  + ln15] = a0[r];
                    gP[par][0][kh][qA][kgrp * 4 + r][16 + ln15] = a1[r];
                    gP[par][0][kh][qB][kgrp * 4 + r][0  + ln15] = a2[r];
                    gP[par][0][kh][qB][kgrp * 4 + r][16 + ln15] = a3[r];
                }
            }
            __syncthreads();
            // ---- phase B: updates (waves 0-1: L0; waves 2-3: L1) ----
            if (tid < 128) {
                if (s < TT) {
                    const int b = tid >> 3, j4v = (tid & 7) * 4;
                    u64t Hh = 0, Hl = 0;
#pragma unroll
                    for (int e = 0; e < 4; e++) {
                        const int col = j4v + e;
                        const float pi = gP[par][0][0][0][b][col] + gP[par][0][1][0][b][col];
                        const float pf = gP[par][0][0][1][b][col] + gP[par][0][1][1][b][col];
                        const float pg = gP[par][0][0][2][b][col] + gP[par][0][1][2][b][col];
                        const float po = gP[par][0][0][3][b][col] + gP[par][0][1][3][b][col];
                        const float iv = sigf(pi), fv = sigf(pf);
                        const float gv = tanhfast(pg), ov = sigf(po);
                        c4[e] = fmaf(fv, c4[e], iv * gv);
                        const float hv = ov * tanhfast(c4[e]);
                        const ushort_t hh = bf16r(hv);
                        const ushort_t hl = bf16r(hv - f32up(hh));
                        Hh |= (u64t)hh << (16 * e);
                        Hl |= (u64t)hl << (16 * e);
                    }
                    const size_t fo = (size_t)(s & (RINGN - 1)) * 1024 + (size_t)w * 128
                                    + (size_t)((tid >> 1) & 3) * 32
                                    + (size_t)(tid >> 3) * 2 + (tid & 1);
                    stq(r1h + fo, Hh); stq(r1l + fo, Hl);
                    asm volatile("s_waitcnt vmcnt(0)" ::: "memory");  // wave-local drain
                    if ((tid & 63) == 0)
                        __hip_atomic_store(seq + (w * 2 + (tid >> 6)) * SEQPAD, s + 1,
                                           __ATOMIC_RELAXED, __HIP_MEMORY_SCOPE_AGENT);
                }
            } else if (tid < 256) {
                if (s >= 1) {
                    const int tl = tid - 128;
                    const int b = tl >> 3, j4v = (tl & 7) * 4;
                    u64t Hh = 0, Hl = 0;
                    f32x4 ho;
#pragma unroll
                    for (int e = 0; e < 4; e++) {
                        const int col = j4v + e;
                        const float pi = gP[par][1][0][0][b][col] + gP[par][1][1][0][b][col];
                        const float pf = gP[par][1][0][1][b][col] + gP[par][1][1][1][b][col];
                        const float pg = gP[par][1][0][2][b][col] + gP[par][1][1][2][b][col];
                        const float po = gP[par][1][0][3][b][col] + gP[par][1][1][3][b][col];
                        const float iv = sigf(pi), fv = sigf(pf);
                        const float gv = tanhfast(pg), ov = sigf(po);
                        c4[e] = fmaf(fv, c4[e], iv * gv);
                        const float hv = ov * tanhfast(c4[e]);
                        ho[e] = hv;
                        const ushort_t hh = bf16r(hv);
                        const ushort_t hl = bf16r(hv - f32up(hh));
                        Hh |= (u64t)hh << (16 * e);
                        Hl |= (u64t)hl << (16 * e);
                    }
                    const size_t fo = (size_t)((s - 1) & (RINGN - 1)) * 1024 + (size_t)w * 128
                                    + (size_t)((tl >> 1) & 3) * 32
                                    + (size_t)(tl >> 3) * 2 + (tl & 1);
                    stq(r2h + fo, Hh); stq(r2l + fo, Hl);
                    asm volatile("s_waitcnt vmcnt(0)" ::: "memory");  // wave-local drain
                    if ((tl & 63) == 0)
                        __hip_atomic_store(seq + (16 + w * 2 + (tl >> 6)) * SEQPAD, s,
                                           __ATOMIC_RELAXED, __HIP_MEMORY_SCOPE_AGENT);
                    // out store AFTER publication: HBM ack off the critical path
                    *(f32x4*)(out + ((size_t)b * TT + (s - 1)) * HH + w * 32 + j4v) = ho;
                }
            }
        }
        // save c-state for next chunk
        {
            const int ut = tid & 127;
            const int b = ut >> 3, j4v = (ut & 7) * 4;
            float* cs = (tid < 128) ? c0s : c1s;
            if (tid < 256) {
                f32x4 cv = {c4[0], c4[1], c4[2], c4[3]};
                *(f32x4*)(cs + (size_t)b * HH + w * 32 + j4v) = cv;
            }
        }
    } else {
        // ---------------- L1 compute (t1 = s-1) ----------------
        const int vv = v - 4;
        const int quad = vv >> 1, kh = vv & 1;
        const int qA = quad * 2, qB = quad * 2 + 1;
        const int r0 = qA * 256 + w * 32 + 0  + ln15;
        const int r1 = qA * 256 + w * 32 + 16 + ln15;
        const int r2 = qB * 256 + w * 32 + 0  + ln15;
        const int r3 = qB * 256 + w * 32 + 16 + ln15;

        bf16x8 I0k0,I0k1,I0k2,I0k3, I1k0,I1k1,I1k2,I1k3;
        bf16x8 I2k0,I2k1,I2k2,I2k3, I3k0,I3k1,I3k2,I3k3;
        bf16x8 H0k0,H0k1,H0k2,H0k3, H1k0,H1k1,H1k2,H1k3;
        bf16x8 H2k0,H2k1,H2k2,H2k3, H3k0,H3k1,H3k2,H3k3;
#define LW1(T, RT)                                                              \
        { const float* pi_ = Wih1 + (size_t)(RT) * HH + kh * 128 + kgrp * 8;    \
          LOADWH(I##T##k0, pi_);      LOADWH(I##T##k1, pi_ + 32);               \
          LOADWH(I##T##k2, pi_ + 64); LOADWH(I##T##k3, pi_ + 96);               \
          const float* ph_ = Whh1 + (size_t)(RT) * HH + kh * 128 + kgrp * 8;    \
          LOADWH(H##T##k0, ph_);      LOADWH(H##T##k1, ph_ + 32);               \
          LOADWH(H##T##k2, ph_ + 64); LOADWH(H##T##k3, ph_ + 96); }
        LW1(0, r0) LW1(1, r1) LW1(2, r2) LW1(3, r3)
#undef LW1
        const float bb0 = (kh == 0) ? b1v[r0] : 0.f;
        const float bb1 = (kh == 0) ? b1v[r1] : 0.f;
        const float bb2 = (kh == 0) ? b1v[r2] : 0.f;
        const float bb3 = (kh == 0) ? b1v[r3] : 0.f;

        for (int s = t0; s < tEnd; s++) {
            const int par = s & 1;
            if (s >= 1) {
                f32x4 a0 = {bb0, bb0, bb0, bb0};
                f32x4 a1 = {bb1, bb1, bb1, bb1};
                f32x4 a2 = {bb2, bb2, bb2, bb2};
                f32x4 a3 = {bb3, bb3, bb3, bb3};
                pollAB(seq, s, s - 1);
                const size_t lanep = (size_t)(kgrp * 16 + ln15) * 2;
                const size_t rb1 = (size_t)((s - 1) & (RINGN - 1)) * 1024 + lanep;
                U2 Ah0, Ah1, Ah2, Ah3, Al0, Al1, Al2, Al3;
#define RL1(k)                                                                  \
                { const size_t o = rb1 + (size_t)(kh * 4 + k) * 128;            \
                  Ah##k.u.a = ldq(r1h + o); Ah##k.u.b = ldq(r1h + o + 1);       \
                  Al##k.u.a = ldq(r1l + o); Al##k.u.b = ldq(r1l + o + 1); }
                RL1(0) RL1(1) RL1(2) RL1(3)
#undef RL1
                if (s >= 2) {
                    const size_t rb2 = (size_t)((s - 2) & (RINGN - 1)) * 1024 + lanep;
                    U2 Ch0, Ch1, Ch2, Ch3, Cl0, Cl1, Cl2, Cl3;
#define RL2(k)                                                                  \
                    { const size_t o = rb2 + (size_t)(kh * 4 + k) * 128;        \
                      Ch##k.u.a = ldq(r2h + o); Ch##k.u.b = ldq(r2h + o + 1);   \
                      Cl##k.u.a = ldq(r2l + o); Cl##k.u.b = ldq(r2l + o + 1); }
                    RL2(0) RL2(1) RL2(2) RL2(3)
#undef RL2
#define MK1(k)                                                                  \
                    MFA(a0, Ah##k.v, I0k##k); MFA(a0, Al##k.v, I0k##k);         \
                    MFA(a1, Ah##k.v, I1k##k); MFA(a1, Al##k.v, I1k##k);         \
                    MFA(a2, Ah##k.v, I2k##k); MFA(a2, Al##k.v, I2k##k);         \
                    MFA(a3, Ah##k.v, I3k##k); MFA(a3, Al##k.v, I3k##k);         \
                    MFA(a0, Ch##k.v, H0k##k); MFA(a0, Cl##k.v, H0k##k);         \
                    MFA(a1, Ch##k.v, H1k##k); MFA(a1, Cl##k.v, H1k##k);         \
                    MFA(a2, Ch##k.v, H2k##k); MFA(a2, Cl##k.v, H2k##k);         \
                    MFA(a3, Ch##k.v, H3k##k); MFA(a3, Cl##k.v, H3k##k);
                    MK1(0) MK1(1) MK1(2) MK1(3)
#undef MK1
                } else {
#define MK1B(k)                                                                 \
                    MFA(a0, Ah##k.v, I0k##k); MFA(a0, Al##k.v, I0k##k);         \
                    MFA(a1, Ah##k.v, I1k##k); MFA(a1, Al##k.v, I1k##k);         \
                    MFA(a2, Ah##k.v, I2k##k); MFA(a2, Al##k.v, I2k##k);         \
                    MFA(a3, Ah##k.v, I3k##k); MFA(a3, Al##k.v, I3k##k);
                    MK1B(0) MK1B(1) MK1B(2) MK1B(3)
#undef MK1B
                }
#pragma unroll
                for (int r = 0; r < 4; r++) {
                    gP[par][1][kh][qA][kgrp * 4 + r][0  + ln15] = a0[r];
                    gP[par][1][kh][qA][kgrp * 4 + r][16 + ln15] = a1[r];
                    gP[par][1][kh][qB][kgrp * 4 + r][0  + ln15] = a2[r];
                    gP[par][1][kh][qB][kgrp * 4 + r][16 + ln15] = a3[r];
                }
            }
            __syncthreads();
            // (phase B runs on waves 0-3; parity buffering removes 2nd barrier)
        }
    }
}

extern "C" void kernel_launch(void* const* d_in, const int* in_sizes, int n_in,
                              void* d_out, int out_size, void* d_ws, size_t ws_size,
                              hipStream_t stream) {
    (void)in_sizes; (void)n_in; (void)out_size;
    const float* x    = (const float*)d_in[0];
    const float* Wih0 = (const float*)d_in[1];
    const float* Whh0 = (const float*)d_in[2];
    const float* b0   = (const float*)d_in[3];
    const float* Wih1 = (const float*)d_in[4];
    const float* Whh1 = (const float*)d_in[5];
    const float* b1   = (const float*)d_in[6];
    float* out = (float*)d_out;

    // ---- workspace carve ----
    char* ws = (char*)d_ws;
    int*   seq = (int*)ws;                      // [32][SEQPAD]
    float* c0s = (float*)(seq + 32 * SEQPAD);   // [16][256]
    float* c1s = c0s + BQ * HH;
    u64t*  r1h = (u64t*)(c1s + BQ * HH);        // rings: [RINGN][1024] u64 each
    u64t*  r1l = r1h + RINGN * 1024;
    u64t*  r2h = r1l + RINGN * 1024;
    u64t*  r2l = r2h + RINGN * 1024;
    float* xw  = (float*)(r2l + RINGN * 1024);  // [TC][1024][16] f32
    const size_t fixedBytes = (size_t)((char*)xw - ws);

    int TC = TT;
    while (TC > 512 && fixedBytes + (size_t)TC * 1024 * BQ * 4 > ws_size) TC >>= 1;

    hipMemsetAsync(ws, 0, fixedBytes, stream);

    for (int t0 = 0; t0 < TT; t0 += TC) {
        xw_gemm<<<dim3((TC / 8) * 4), 256, 0, stream>>>(x, Wih0, b0, xw, t0);
        const int tEnd = t0 + TC + ((t0 + TC == TT) ? 1 : 0);
        lstm_ring<<<8, 512, 0, stream>>>(Whh0, Wih1, Whh1, b1, xw,
                                         r1h, r1l, r2h, r2l,
                                         out, c0s, c1s, seq, t0, tEnd);
    }
}